// Round 12
// baseline (258.863 us; speedup 1.0000x reference)
//
#include <hip/hip_runtime.h>
#include <hip/hip_bf16.h>

// ---------------------------------------------------------------------------
// Equivariant conv block. MFMA 32x32x16 implicit GEMM.
// R20 WIN: build_w restructure -20.7us (272.9->252.2), prediction matched.
// Non-conv budget still ~145us but invisible (top-5 saturated by 30x conv
// @107). R21: DIAGNOSTIC SPLIT, perf-neutral by tap math (1.70us/tap):
// conv -> two dispatches via ks_base (KSN=16): launch1 ks0-7 (max 35 taps
// ~60us), launch2 ks8-15 (uniform 28 taps ~48us). Top-5 ceiling drops to
// ~60 -> any hidden kernel >48us surfaces with counters. Combine reads 16
// slices (+3us). Everything else byte-identical to verified R20.
// ---------------------------------------------------------------------------

using f4  = __attribute__((ext_vector_type(4)))  float;
using f16v= __attribute__((ext_vector_type(16))) float;
using s8  = __attribute__((ext_vector_type(8)))  short;  // 8 bf16

#define C_TOT 160
#define PZ_   37
#define NTAP  343
#define NROW  (4 * PZ_ * PZ_)   // 5476 (b,z,y) rows per chunk
#define KSN   16
#define SLICE_E 1048576         // bf16 elems per partial slice (4*64*4096)

// conv LDS: A-stripe rows (1216 B data + 16 pad = 1232 stride), split by
// y'-parity: A_E = 19 rows (y'=0,2,..,36) at [0, 23552); A_O = 18 rows at
// [23552, 46080). B at 46080: [kx7][nt2][cg2][n32][16B], dbuf 2x14336.
// Total 74752 B (x2 blocks/CU = 149504 <= 160KB).
// Epilogue reuses [0, 33792) as yb[64n][33 f4].
#define AROW    1232
#define AE_ROWS 19
#define AO_ROWS 18
#define AO_OFF  23552
#define B_OFF   46080
#define BSZ     14336
#define LDS_SZ  (B_OFF + 2 * BSZ)   // 74752

__device__ __forceinline__ void gl_lds16(const void* g, void* l) {
    __builtin_amdgcn_global_load_lds(
        (const __attribute__((address_space(1))) unsigned int*)g,
        (__attribute__((address_space(3))) unsigned int*)l, 16, 0, 0);
}

__device__ __forceinline__ void pair_ij(int p, int& i, int& j) {
    if (p < 3)      { i = p; j = p; }
    else if (p == 3){ i = 0; j = 1; }
    else if (p == 4){ i = 0; j = 2; }
    else            { i = 1; j = 2; }
}

struct bf2 { __hip_bfloat16 x, y; };
struct bh4 { __hip_bfloat16 x, y, z, w; };

// ---------------------------------------------------------------------------
// build_w (R20): grid 343 = 1 block/tap, 192 threads. Threads 0..159 own
// channel-column c and compute all 64 n with register-hoisted basis combos.
// wl[chunk][tap][n][16ch] layout unchanged.
// ---------------------------------------------------------------------------
__global__ void build_w_kernel(
    const float* __restrict__ b_ss, const float* __restrict__ w_ss,
    const float* __restrict__ b_sv, const float* __restrict__ w_sv,
    const float* __restrict__ b_st, const float* __restrict__ w_st,
    const float* __restrict__ b_vs, const float* __restrict__ w_vs,
    const float* __restrict__ b_vv, const float* __restrict__ w_vv,
    const float* __restrict__ b_vt, const float* __restrict__ w_vt,
    __hip_bfloat16* __restrict__ wl)
{
    __shared__ float S[13056];
    const int tid = threadIdx.x;          // 0..191
    const int tap = blockIdx.x;           // 0..342
    float* L = S;                         // 750
    float* W = S + 768;                   // 12288
    for (int r = tid; r < 750; r += 192) {
        float v;
        if (r < 3)        v = b_ss[r * NTAP + tap];
        else if (r < 12)  v = b_sv[(r - 3) * NTAP + tap];
        else if (r < 93)  v = b_st[(r - 12) * NTAP + tap];
        else if (r < 102) v = b_vs[(r - 93) * NTAP + tap];
        else if (r < 183) v = b_vv[(r - 102) * NTAP + tap];
        else              v = b_vt[(r - 183) * NTAP + tap];
        L[r] = v;
    }
    for (int r = tid; r < 12288; r += 192) {
        float v;
        if (r < 768)       v = w_ss[r];
        else if (r < 1536) v = w_sv[r - 768];
        else if (r < 3840) v = w_st[r - 1536];
        else if (r < 4608) v = w_vs[r - 3840];
        else if (r < 6912) v = w_vv[r - 4608];
        else               v = w_vt[r - 6912];
        W[r] = v;
    }
    __syncthreads();

    if (tid < 160) {
        const int c = tid;
        const int chunk = c >> 4, cw = c & 15;
        __hip_bfloat16* dst = wl + ((size_t)chunk * NTAP + tap) * 1024 + cw;

        if (c < 16) {
            // ---- class A (scalar input ch) ----
            const float l0 = L[0], l1 = L[1], l2 = L[2];
#pragma unroll
            for (int n = 0; n < 16; ++n) {
                const float* wr = &W[(n * 16 + c) * 3];
                dst[n * 16] = __float2bfloat16(wr[0]*l0 + wr[1]*l1 + wr[2]*l2);
            }
            float bv[3][3];
#pragma unroll
            for (int dn = 0; dn < 3; ++dn)
#pragma unroll
                for (int t = 0; t < 3; ++t) bv[dn][t] = L[93 + t*3 + dn];
#pragma unroll
            for (int u = 0; u < 16; ++u) {
                const float* wr = &W[3840 + (u * 16 + c) * 3];
                const float w0 = wr[0], w1 = wr[1], w2 = wr[2];
#pragma unroll
                for (int dn = 0; dn < 3; ++dn)
                    dst[(16 + u*3 + dn) * 16] = __float2bfloat16(
                        w0*bv[dn][0] + w1*bv[dn][1] + w2*bv[dn][2]);
            }
        } else if (c < 64) {
            // ---- class B (vector input ch) ----
            const int mm = (c - 16) / 3, di = (c - 16) % 3;
            float bs0[3];
#pragma unroll
            for (int t = 0; t < 3; ++t) bs0[t] = L[3 + t*3 + di];
#pragma unroll
            for (int n = 0; n < 16; ++n) {
                const float* wr = &W[768 + (n * 16 + mm) * 3];
                dst[n * 16] = __float2bfloat16(
                    wr[0]*bs0[0] + wr[1]*bs0[1] + wr[2]*bs0[2]);
            }
            float bv[3][9];
#pragma unroll
            for (int dn = 0; dn < 3; ++dn)
#pragma unroll
                for (int t = 0; t < 9; ++t)
                    bv[dn][t] = L[102 + (t*3 + dn)*3 + di];
#pragma unroll
            for (int u = 0; u < 16; ++u) {
                const float* wr = &W[4608 + (u * 16 + mm) * 9];
                float a0 = 0.f, a1 = 0.f, a2 = 0.f;
#pragma unroll
                for (int t = 0; t < 9; ++t) {
                    const float wv = wr[t];
                    a0 += wv * bv[0][t]; a1 += wv * bv[1][t]; a2 += wv * bv[2][t];
                }
                dst[(16 + u*3 + 0) * 16] = __float2bfloat16(a0);
                dst[(16 + u*3 + 1) * 16] = __float2bfloat16(a1);
                dst[(16 + u*3 + 2) * 16] = __float2bfloat16(a2);
            }
        } else {
            // ---- class C (tensor input ch) ----
            const int q = c - 64, mm = q / 6, p = q % 6;
            int i, jj; pair_ij(p, i, jj);
            const int d1 = i*3 + jj, d2 = jj*3 + i;
            const bool dbl = (i != jj);
            float bs0[9];
#pragma unroll
            for (int t = 0; t < 9; ++t) {
                float b = L[12 + t*9 + d1];
                if (dbl) b += L[12 + t*9 + d2];
                bs0[t] = b;
            }
#pragma unroll
            for (int n = 0; n < 16; ++n) {
                const float* wr = &W[1536 + (n * 16 + mm) * 9];
                float acc = 0.f;
#pragma unroll
                for (int t = 0; t < 9; ++t) acc += wr[t] * bs0[t];
                dst[n * 16] = __float2bfloat16(acc);
            }
            float bv0[21], bv1[21], bv2[21];
#pragma unroll
            for (int t = 0; t < 21; ++t) {
                float x0 = L[183 + (t*3 + 0)*9 + d1];
                float x1 = L[183 + (t*3 + 1)*9 + d1];
                float x2 = L[183 + (t*3 + 2)*9 + d1];
                if (dbl) {
                    x0 += L[183 + (t*3 + 0)*9 + d2];
                    x1 += L[183 + (t*3 + 1)*9 + d2];
                    x2 += L[183 + (t*3 + 2)*9 + d2];
                }
                bv0[t] = x0; bv1[t] = x1; bv2[t] = x2;
            }
#pragma unroll
            for (int u = 0; u < 16; ++u) {
                const float* wr = &W[6912 + (u * 16 + mm) * 21];
                float a0 = 0.f, a1 = 0.f, a2 = 0.f;
#pragma unroll
                for (int t = 0; t < 21; ++t) {
                    const float wv = wr[t];
                    a0 += wv * bv0[t]; a1 += wv * bv1[t]; a2 += wv * bv2[t];
                }
                dst[(16 + u*3 + 0) * 16] = __float2bfloat16(a0);
                dst[(16 + u*3 + 1) * 16] = __float2bfloat16(a1);
                dst[(16 + u*3 + 2) * 16] = __float2bfloat16(a2);
            }
        }
    }
}

// ---------------------------------------------------------------------------
// build_xt: bid = (b*37 + z)*37 + y. xt[chunk][brow][s][16ch].
// Small shared (8448 B) -> 8 blocks/CU (wave-capped). Coalesced writes.
// ---------------------------------------------------------------------------
__global__ void build_xt_kernel(
    const float* __restrict__ sv, __hip_bfloat16* __restrict__ xt)
{
    __shared__ float row[2112];                  // 32*66
    const int tid = threadIdx.x;
    const int bid = blockIdx.x;                  // (b*37 + z)*37 + y
    const int y = bid % 37, z = (bid / 37) % 37, b = bid / 1369;
    const bool interior = (z >= 3 && z < 35 && y >= 3 && y < 35);
    if (interior) {
        const float* src = sv + (size_t)b * 2097152 + (z-3) * 1024 + (y-3) * 32;
        for (int f = tid; f < 2048; f += 256) {
            int ch = f >> 5, x = f & 31;
            row[x * 66 + ch] = src[(size_t)ch * 32768 + x];
        }
    }
    __syncthreads();
    for (int e2 = tid; e2 < 3040; e2 += 256) {
        const int chunk = e2 / 304;              // 0..9
        const int r     = e2 - chunk * 304;      // 0..303 (elem-pair idx)
        const int s     = r >> 3;                // 0..37
        const int cw    = (r & 7) * 2;
        const int c     = chunk * 16 + cw;
        float v0 = 0.f, v1 = 0.f;
        if (interior && s >= 3 && s < 35) {
            const int x = s - 3;
            if (c < 64) {
                v0 = row[x * 66 + c];
                v1 = row[x * 66 + c + 1];
            } else {
                int q = c - 64, u = q / 6, p = q % 6, i, j;
                pair_ij(p, i, j);
                v0 = row[x * 66 + 16 + u * 3 + i] * row[x * 66 + 16 + u * 3 + j];
                pair_ij(p + 1, i, j);
                v1 = row[x * 66 + 16 + u * 3 + i] * row[x * 66 + 16 + u * 3 + j];
            }
        }
        bf2 w{__float2bfloat16(v0), __float2bfloat16(v1)};
        *(bf2*)(xt + ((size_t)chunk * NROW + bid) * 608 + r * 2) = w;
    }
}

// ---------------------------------------------------------------------------
// Conv (R13 structure, verified ~107us total). R21: split into two launches
// via ks_base (0 then 8); KSN=16 K-split. Grid 512/launch (2 blocks/CU).
// Block = (b, oz, ks_local). Groups g = ks..69 step 16; per group A-stripe
// staged once, parity split; taps ky = 1,3,5,0,2,4,6. B staged per tap
// (LDS dbuf). One barrier per tap.
// ---------------------------------------------------------------------------
__global__ __launch_bounds__(256, 2) void conv_mfma_kernel(
    const __hip_bfloat16* __restrict__ xt,
    const __hip_bfloat16* __restrict__ wl,
    __hip_bfloat16* __restrict__ y4b,
    int ks_base)
{
    __shared__ __align__(16) char lds[LDS_SZ];

    // T1 XCD swizzle: grid = 512 = 8 XCDs x 64.
    const int phys = blockIdx.x;
    const int bid  = (phys & 7) * 64 + (phys >> 3);

    const int low3 = bid & 7;
    const int rest = bid >> 3;
    const int ksl  = rest & 7;                  // ks_local 0..7
    const int ks   = ks_base + ksl;             // 0..15
    const int mb   = (rest >> 3) * 8 + low3;    // 0..63
    const int b    = mb >> 4;                   // 0..3
    const int oz   = mb & 15;                   // z-out 0..15

    const int tid  = threadIdx.x;
    const int w    = tid >> 6;          // x-quarter
    const int lane = tid & 63;
    const int m    = lane & 31;
    const int h    = lane >> 5;         // k-half (8-ch group)

    // ---- per-lane invariant staging source offsets (elements) ----
    int invAE[6]; int nAE = 0;
#pragma unroll
    for (int k = 0; k < 6; ++k) {
        const int i = w + 4 * k;
        if (i < 23) {
            const int o = i * 1024 + lane * 16;
            int r = o / AROW;
            int rem = o - r * AROW;
            if (r > AE_ROWS - 1) { r = AE_ROWS - 1; rem = 0; }
            if (rem >= 1216) rem = 0;
            const int s  = rem >> 5;
            const int cg = ((rem >> 4) & 1) ^ ((s >> 1) & 1);
            invAE[k] = (2 * r) * 608 + s * 16 + cg * 8;      // y' = 2r
            nAE = k + 1;
        }
    }
    int invAO[6]; int nAO = 0;
#pragma unroll
    for (int k = 0; k < 6; ++k) {
        const int i = w + 4 * k;
        if (i < 22) {
            const int o = i * 1024 + lane * 16;
            int r = o / AROW;
            int rem = o - r * AROW;
            if (r > AO_ROWS - 1) { r = AO_ROWS - 1; rem = 0; }
            if (rem >= 1216) rem = 0;
            const int s  = rem >> 5;
            const int cg = ((rem >> 4) & 1) ^ ((s >> 1) & 1);
            invAO[k] = (2 * r + 1) * 608 + s * 16 + cg * 8;  // y' = 2r+1
            nAO = k + 1;
        }
    }
    int invB[4]; int nB = 0;
#pragma unroll
    for (int k = 0; k < 4; ++k) {
        const int i = w + 4 * k;
        if (i < 14) {
            const int kx = i >> 1, nt = i & 1;
            invB[k] = kx * 1024 + (nt * 32 + m) * 16 + h * 8;
            nB = k + 1;
        }
    }

    f16v acc[2][2];
    for (int t = 0; t < 2; ++t)
        for (int n = 0; n < 2; ++n)
            for (int k = 0; k < 16; ++k) acc[t][n][k] = 0.f;

    const int rA0   = ((m >> 4) << 2) + ((m >> 2) & 3);   // yo base 0..7
    const int sbase = (w << 3) + ((m & 3) << 1);          // + kx -> x slot

    auto stageAE = [&](int g) {
        const int chunk = g / 7, kz = g - chunk * 7;
        const size_t u = ((size_t)chunk * NROW
                        + (size_t)(b * PZ_ + 2 * oz + kz) * PZ_) * 608;
#pragma unroll
        for (int k = 0; k < 6; ++k)
            if (k < nAE) gl_lds16(xt + u + invAE[k], lds + (w + 4 * k) * 1024);
    };
    auto stageAO = [&](int g) {
        const int chunk = g / 7, kz = g - chunk * 7;
        const size_t u = ((size_t)chunk * NROW
                        + (size_t)(b * PZ_ + 2 * oz + kz) * PZ_) * 608;
#pragma unroll
        for (int k = 0; k < 6; ++k)
            if (k < nAO) gl_lds16(xt + u + invAO[k], lds + AO_OFF + (w + 4 * k) * 1024);
    };
    auto stageB = [&](int g, int kyv, int bsel) {
        const int chunk = g / 7, kz = g - chunk * 7;
        const size_t u = ((size_t)chunk * NTAP + (size_t)(kz * 7 + kyv) * 7) * 1024;
        char* dst = lds + B_OFF + bsel * BSZ;
#pragma unroll
        for (int k = 0; k < 4; ++k)
            if (k < nB) gl_lds16(wl + u + invB[k], dst + (w + 4 * k) * 1024);
    };

    auto compute = [&](int ky, int bsel) {
        const int abase = (ky & 1) ? AO_OFF : 0;
        const char* abp = lds + abase + (rA0 + (ky >> 1)) * AROW;
        const char* bbp = lds + B_OFF + bsel * BSZ;
#pragma unroll
        for (int kx = 0; kx < 7; ++kx) {
            const int s   = sbase + kx;
            const int cgp = h ^ ((s >> 1) & 1);
            const char* ap = abp + s * 32 + cgp * 16;
            const s8 a0 = *(const s8*)(ap);
            const s8 a1 = *(const s8*)(ap + 8 * AROW);
            const char* bp = bbp + kx * 2048 + h * 512 + m * 16;
            const s8 b0 = *(const s8*)(bp);
            const s8 b1 = *(const s8*)(bp + 1024);
            acc[0][0] = __builtin_amdgcn_mfma_f32_32x32x16_bf16(a0, b0, acc[0][0], 0, 0, 0);
            acc[0][1] = __builtin_amdgcn_mfma_f32_32x32x16_bf16(a0, b1, acc[0][1], 0, 0, 0);
            acc[1][0] = __builtin_amdgcn_mfma_f32_32x32x16_bf16(a1, b0, acc[1][0], 0, 0, 0);
            acc[1][1] = __builtin_amdgcn_mfma_f32_32x32x16_bf16(a1, b1, acc[1][1], 0, 0, 0);
        }
    };

    // ---- main loop: groups g = ks..69 step 16; taps ky order 1,3,5,0,2,4,6 ----
    const int G = (70 - ks + KSN - 1) / KSN;   // 5 (ks 0-5) or 4
    const int T = G * 7;
    stageAO(ks);
    stageB(ks, 1, 0);
    __syncthreads();
    int bB = 0;
    for (int t = 0; t < T; ++t) {
        const int gi = t / 7, p = t - gi * 7;
        const int g  = ks + gi * KSN;
        const int ky = (p < 3) ? (2 * p + 1) : (2 * (p - 3));
        const int tn = t + 1;
        if (tn < T) {
            const int gin = tn / 7, pn = tn - gin * 7;
            const int kyn = (pn < 3) ? (2 * pn + 1) : (2 * (pn - 3));
            stageB(ks + gin * KSN, kyn, bB ^ 1);
        }
        if (p == 0) stageAE(g);                        // compute reads A_O
        else if (p == 3 && g + KSN < 70) stageAO(g + KSN);  // compute reads A_E
        compute(ky, bB);
        __syncthreads();                               // drains lds-DMA
        bB ^= 1;
    }

    // ---- epilogue: two-pass LDS transpose, coalesced bf16 partial stores ----
    // C/D 32x32: col(n)=lane&31, row m32=(reg&3)+8*(reg>>2)+4*h  [m74/m101]
    const int nl = lane & 31;
    f4* yb = (f4*)lds;                  // [64n][33 f4] padded = 33792 B
    __hip_bfloat16* dst0 = y4b + (size_t)ks * SLICE_E + (size_t)(b * 64) * 4096;
#pragma unroll
    for (int t = 0; t < 2; ++t) {       // yo-half
        __syncthreads();                // prior readers (or compute) done
#pragma unroll
        for (int nt = 0; nt < 2; ++nt) {
            const int n = nt * 32 + nl;
#pragma unroll
            for (int q = 0; q < 4; ++q) {
                const int rr = 2 * q + h;
                f4 v = { acc[t][nt][4*q], acc[t][nt][4*q+1],
                         acc[t][nt][4*q+2], acc[t][nt][4*q+3] };
                yb[n * 33 + rr * 4 + w] = v;
            }
        }
        __syncthreads();
        for (int j = tid; j < 2048; j += 256) {
            const int n  = j >> 5, sp = j & 31;    // sp = rr*4 + wq
            f4 v = yb[n * 33 + sp];
            const int rr = sp >> 2, wq = sp & 3;
            const int yo = t * 8 + (rr >> 2) * 4 + (rr & 3);
            bh4 p{__float2bfloat16(v.x), __float2bfloat16(v.y),
                  __float2bfloat16(v.z), __float2bfloat16(v.w)};
            *(bh4*)(dst0 + (size_t)n * 4096 + oz * 256 + yo * 16 + wq * 4) = p;
        }
    }
}

// ---------------------------------------------------------------------------
// Combine KSN bf16 partials -> f32 yc + per-(n,b) sum of squares. 256 blocks.
// ---------------------------------------------------------------------------
__global__ void combine_reduce_kernel(const __hip_bfloat16* __restrict__ y4b,
                                      float* __restrict__ yc,
                                      float* __restrict__ sums2)
{
    const int n = blockIdx.x & 63, q = blockIdx.x >> 6;
    const size_t base = ((size_t)q * 64 + n) * 4096;
    float s = 0.f;
    for (int i = threadIdx.x; i < 1024; i += 256) {
        const size_t off = base + (size_t)i * 4;
        f4 v = {0.f, 0.f, 0.f, 0.f};
#pragma unroll
        for (int k = 0; k < KSN; ++k) {
            bh4 r = *(const bh4*)(y4b + off + (size_t)k * SLICE_E);
            v.x += (float)r.x; v.y += (float)r.y;
            v.z += (float)r.z; v.w += (float)r.w;
        }
        *(f4*)(yc + off) = v;
        s += v.x * v.x + v.y * v.y + v.z * v.z + v.w * v.w;
    }
    __shared__ float red[256];
    red[threadIdx.x] = s;
    __syncthreads();
    for (int st = 128; st > 0; st >>= 1) {
        if (threadIdx.x < st) red[threadIdx.x] += red[threadIdx.x + st];
        __syncthreads();
    }
    if (threadIdx.x == 0) sums2[n * 4 + q] = red[0];
}

// ---------------------------------------------------------------------------
__global__ void finalize_kernel(const float* __restrict__ yc,
                                const float* __restrict__ sums2,
                                const float* __restrict__ g_s,
                                const float* __restrict__ g_v,
                                const float* __restrict__ bias_s,
                                float* __restrict__ out)
{
    const int idx = blockIdx.x * 256 + threadIdx.x;   // exact grid, 1M
    const int n = (idx >> 12) & 63;
    float v = yc[idx];
    if (n < 16) {
        float sum = sums2[n*4] + sums2[n*4+1] + sums2[n*4+2] + sums2[n*4+3];
        float var = sum * (1.0f / 16384.0f);
        float sc  = g_s[n] / sqrtf(var + 1e-5f);
        v = fmaxf(v * sc + bias_s[n], 0.f);
    } else {
        int u = (n - 16) / 3;
        float sum = 0.f;
        for (int k = 0; k < 12; ++k) sum += sums2[(16 + u * 3) * 4 + k];
        float var = sum * (1.0f / 49152.0f);
        v = v * (g_v[u] / sqrtf(var + 1e-5f));
    }
    out[idx] = v;
}

// ---------------------------------------------------------------------------
extern "C" void kernel_launch(void* const* d_in, const int* in_sizes, int n_in,
                              void* d_out, int out_size, void* d_ws, size_t ws_size,
                              hipStream_t stream)
{
    const float* sv    = (const float*)d_in[0];
    const float* b_ss  = (const float*)d_in[1];
    const float* w_ss  = (const float*)d_in[2];
    const float* b_sv  = (const float*)d_in[3];
    const float* w_sv  = (const float*)d_in[4];
    const float* b_st  = (const float*)d_in[5];
    const float* w_st  = (const float*)d_in[6];
    const float* b_vs  = (const float*)d_in[7];
    const float* w_vs  = (const float*)d_in[8];
    const float* b_vv  = (const float*)d_in[9];
    const float* w_vv  = (const float*)d_in[10];
    const float* b_vt  = (const float*)d_in[11];
    const float* w_vt  = (const float*)d_in[12];
    const float* bn_gs = (const float*)d_in[13];
    const float* bn_gv = (const float*)d_in[14];
    const float* bias_s= (const float*)d_in[15];
    float* out = (float*)d_out;

    char* ws = (char*)d_ws;
    constexpr size_t XT_BYTES = (size_t)10 * NROW * 1216;      // 66,588,160
    constexpr size_t WL_BYTES = (size_t)10 * NTAP * 2048;      //  7,024,640
    constexpr size_t Y4_BYTES = (size_t)KSN * SLICE_E * 2;     // 33,554,432
    constexpr size_t YC_BYTES = (size_t)4 * 64 * 4096 * 4;     //  4,194,304

    __hip_bfloat16* xt  = (__hip_bfloat16*)ws;
    __hip_bfloat16* wl  = (__hip_bfloat16*)(ws + XT_BYTES);
    __hip_bfloat16* y4b = (__hip_bfloat16*)(ws + XT_BYTES + WL_BYTES);
    float* yc    = (float*)(ws + XT_BYTES + WL_BYTES + Y4_BYTES);
    float* sums2 = (float*)(ws + XT_BYTES + WL_BYTES + Y4_BYTES + YC_BYTES);

    build_xt_kernel<<<5476, 256, 0, stream>>>(sv, xt);
    build_w_kernel<<<343, 192, 0, stream>>>(
        b_ss, w_ss, b_sv, w_sv, b_st, w_st, b_vs, w_vs, b_vv, w_vv,
        b_vt, w_vt, wl);
    conv_mfma_kernel<<<512, 256, 0, stream>>>(xt, wl, y4b, 0);
    conv_mfma_kernel<<<512, 256, 0, stream>>>(xt, wl, y4b, 8);
    combine_reduce_kernel<<<256, 256, 0, stream>>>(y4b, yc, sums2);
    finalize_kernel<<<4096, 256, 0, stream>>>(yc, sums2, bn_gs, bn_gv, bias_s, out);
}

// Round 13
// 258.208 us; speedup vs baseline: 1.0025x; 1.0025x over previous
//
#include <hip/hip_runtime.h>
#include <hip/hip_bf16.h>

// ---------------------------------------------------------------------------
// Equivariant conv block. MFMA 32x32x16 implicit GEMM.
// R21 diagnostic: no hidden kernel >=49us; launch overhead ~0 (graph).
// R22 = R20 base (252.2) with (1) conv reverted to unified KSN=8 single
// launch (verified 107us), (2) combine+finalize FUSED via last-block spin
// (grid 256 all-resident; device-scope atomics; counter memset per launch):
// partial sums kept in REGISTERS across the grid sync -> yc 4MB write +
// 4MB read eliminated + one launch removed.
// ---------------------------------------------------------------------------

using f4  = __attribute__((ext_vector_type(4)))  float;
using f16v= __attribute__((ext_vector_type(16))) float;
using s8  = __attribute__((ext_vector_type(8)))  short;  // 8 bf16

#define C_TOT 160
#define PZ_   37
#define NTAP  343
#define NROW  (4 * PZ_ * PZ_)   // 5476 (b,z,y) rows per chunk
#define KSN   8
#define SLICE_E 1048576         // bf16 elems per partial slice (4*64*4096)

#define AROW    1232
#define AE_ROWS 19
#define AO_ROWS 18
#define AO_OFF  23552
#define B_OFF   46080
#define BSZ     14336
#define LDS_SZ  (B_OFF + 2 * BSZ)   // 74752

__device__ __forceinline__ void gl_lds16(const void* g, void* l) {
    __builtin_amdgcn_global_load_lds(
        (const __attribute__((address_space(1))) unsigned int*)g,
        (__attribute__((address_space(3))) unsigned int*)l, 16, 0, 0);
}

__device__ __forceinline__ void pair_ij(int p, int& i, int& j) {
    if (p < 3)      { i = p; j = p; }
    else if (p == 3){ i = 0; j = 1; }
    else if (p == 4){ i = 0; j = 2; }
    else            { i = 1; j = 2; }
}

struct bf2 { __hip_bfloat16 x, y; };
struct bh4 { __hip_bfloat16 x, y, z, w; };

// ---------------------------------------------------------------------------
// build_w (R20): grid 343 = 1 block/tap, 192 threads. Threads 0..159 own
// channel-column c and compute all 64 n with register-hoisted basis combos.
// ---------------------------------------------------------------------------
__global__ void build_w_kernel(
    const float* __restrict__ b_ss, const float* __restrict__ w_ss,
    const float* __restrict__ b_sv, const float* __restrict__ w_sv,
    const float* __restrict__ b_st, const float* __restrict__ w_st,
    const float* __restrict__ b_vs, const float* __restrict__ w_vs,
    const float* __restrict__ b_vv, const float* __restrict__ w_vv,
    const float* __restrict__ b_vt, const float* __restrict__ w_vt,
    __hip_bfloat16* __restrict__ wl)
{
    __shared__ float S[13056];
    const int tid = threadIdx.x;          // 0..191
    const int tap = blockIdx.x;           // 0..342
    float* L = S;                         // 750
    float* W = S + 768;                   // 12288
    for (int r = tid; r < 750; r += 192) {
        float v;
        if (r < 3)        v = b_ss[r * NTAP + tap];
        else if (r < 12)  v = b_sv[(r - 3) * NTAP + tap];
        else if (r < 93)  v = b_st[(r - 12) * NTAP + tap];
        else if (r < 102) v = b_vs[(r - 93) * NTAP + tap];
        else if (r < 183) v = b_vv[(r - 102) * NTAP + tap];
        else              v = b_vt[(r - 183) * NTAP + tap];
        L[r] = v;
    }
    for (int r = tid; r < 12288; r += 192) {
        float v;
        if (r < 768)       v = w_ss[r];
        else if (r < 1536) v = w_sv[r - 768];
        else if (r < 3840) v = w_st[r - 1536];
        else if (r < 4608) v = w_vs[r - 3840];
        else if (r < 6912) v = w_vv[r - 4608];
        else               v = w_vt[r - 6912];
        W[r] = v;
    }
    __syncthreads();

    if (tid < 160) {
        const int c = tid;
        const int chunk = c >> 4, cw = c & 15;
        __hip_bfloat16* dst = wl + ((size_t)chunk * NTAP + tap) * 1024 + cw;

        if (c < 16) {
            const float l0 = L[0], l1 = L[1], l2 = L[2];
#pragma unroll
            for (int n = 0; n < 16; ++n) {
                const float* wr = &W[(n * 16 + c) * 3];
                dst[n * 16] = __float2bfloat16(wr[0]*l0 + wr[1]*l1 + wr[2]*l2);
            }
            float bv[3][3];
#pragma unroll
            for (int dn = 0; dn < 3; ++dn)
#pragma unroll
                for (int t = 0; t < 3; ++t) bv[dn][t] = L[93 + t*3 + dn];
#pragma unroll
            for (int u = 0; u < 16; ++u) {
                const float* wr = &W[3840 + (u * 16 + c) * 3];
                const float w0 = wr[0], w1 = wr[1], w2 = wr[2];
#pragma unroll
                for (int dn = 0; dn < 3; ++dn)
                    dst[(16 + u*3 + dn) * 16] = __float2bfloat16(
                        w0*bv[dn][0] + w1*bv[dn][1] + w2*bv[dn][2]);
            }
        } else if (c < 64) {
            const int mm = (c - 16) / 3, di = (c - 16) % 3;
            float bs0[3];
#pragma unroll
            for (int t = 0; t < 3; ++t) bs0[t] = L[3 + t*3 + di];
#pragma unroll
            for (int n = 0; n < 16; ++n) {
                const float* wr = &W[768 + (n * 16 + mm) * 3];
                dst[n * 16] = __float2bfloat16(
                    wr[0]*bs0[0] + wr[1]*bs0[1] + wr[2]*bs0[2]);
            }
            float bv[3][9];
#pragma unroll
            for (int dn = 0; dn < 3; ++dn)
#pragma unroll
                for (int t = 0; t < 9; ++t)
                    bv[dn][t] = L[102 + (t*3 + dn)*3 + di];
#pragma unroll
            for (int u = 0; u < 16; ++u) {
                const float* wr = &W[4608 + (u * 16 + mm) * 9];
                float a0 = 0.f, a1 = 0.f, a2 = 0.f;
#pragma unroll
                for (int t = 0; t < 9; ++t) {
                    const float wv = wr[t];
                    a0 += wv * bv[0][t]; a1 += wv * bv[1][t]; a2 += wv * bv[2][t];
                }
                dst[(16 + u*3 + 0) * 16] = __float2bfloat16(a0);
                dst[(16 + u*3 + 1) * 16] = __float2bfloat16(a1);
                dst[(16 + u*3 + 2) * 16] = __float2bfloat16(a2);
            }
        } else {
            const int q = c - 64, mm = q / 6, p = q % 6;
            int i, jj; pair_ij(p, i, jj);
            const int d1 = i*3 + jj, d2 = jj*3 + i;
            const bool dbl = (i != jj);
            float bs0[9];
#pragma unroll
            for (int t = 0; t < 9; ++t) {
                float b = L[12 + t*9 + d1];
                if (dbl) b += L[12 + t*9 + d2];
                bs0[t] = b;
            }
#pragma unroll
            for (int n = 0; n < 16; ++n) {
                const float* wr = &W[1536 + (n * 16 + mm) * 9];
                float acc = 0.f;
#pragma unroll
                for (int t = 0; t < 9; ++t) acc += wr[t] * bs0[t];
                dst[n * 16] = __float2bfloat16(acc);
            }
            float bv0[21], bv1[21], bv2[21];
#pragma unroll
            for (int t = 0; t < 21; ++t) {
                float x0 = L[183 + (t*3 + 0)*9 + d1];
                float x1 = L[183 + (t*3 + 1)*9 + d1];
                float x2 = L[183 + (t*3 + 2)*9 + d1];
                if (dbl) {
                    x0 += L[183 + (t*3 + 0)*9 + d2];
                    x1 += L[183 + (t*3 + 1)*9 + d2];
                    x2 += L[183 + (t*3 + 2)*9 + d2];
                }
                bv0[t] = x0; bv1[t] = x1; bv2[t] = x2;
            }
#pragma unroll
            for (int u = 0; u < 16; ++u) {
                const float* wr = &W[6912 + (u * 16 + mm) * 21];
                float a0 = 0.f, a1 = 0.f, a2 = 0.f;
#pragma unroll
                for (int t = 0; t < 21; ++t) {
                    const float wv = wr[t];
                    a0 += wv * bv0[t]; a1 += wv * bv1[t]; a2 += wv * bv2[t];
                }
                dst[(16 + u*3 + 0) * 16] = __float2bfloat16(a0);
                dst[(16 + u*3 + 1) * 16] = __float2bfloat16(a1);
                dst[(16 + u*3 + 2) * 16] = __float2bfloat16(a2);
            }
        }
    }
}

// ---------------------------------------------------------------------------
// build_xt: bid = (b*37 + z)*37 + y. xt[chunk][brow][s][16ch].
// ---------------------------------------------------------------------------
__global__ void build_xt_kernel(
    const float* __restrict__ sv, __hip_bfloat16* __restrict__ xt)
{
    __shared__ float row[2112];                  // 32*66
    const int tid = threadIdx.x;
    const int bid = blockIdx.x;                  // (b*37 + z)*37 + y
    const int y = bid % 37, z = (bid / 37) % 37, b = bid / 1369;
    const bool interior = (z >= 3 && z < 35 && y >= 3 && y < 35);
    if (interior) {
        const float* src = sv + (size_t)b * 2097152 + (z-3) * 1024 + (y-3) * 32;
        for (int f = tid; f < 2048; f += 256) {
            int ch = f >> 5, x = f & 31;
            row[x * 66 + ch] = src[(size_t)ch * 32768 + x];
        }
    }
    __syncthreads();
    for (int e2 = tid; e2 < 3040; e2 += 256) {
        const int chunk = e2 / 304;              // 0..9
        const int r     = e2 - chunk * 304;      // 0..303
        const int s     = r >> 3;                // 0..37
        const int cw    = (r & 7) * 2;
        const int c     = chunk * 16 + cw;
        float v0 = 0.f, v1 = 0.f;
        if (interior && s >= 3 && s < 35) {
            const int x = s - 3;
            if (c < 64) {
                v0 = row[x * 66 + c];
                v1 = row[x * 66 + c + 1];
            } else {
                int q = c - 64, u = q / 6, p = q % 6, i, j;
                pair_ij(p, i, j);
                v0 = row[x * 66 + 16 + u * 3 + i] * row[x * 66 + 16 + u * 3 + j];
                pair_ij(p + 1, i, j);
                v1 = row[x * 66 + 16 + u * 3 + i] * row[x * 66 + 16 + u * 3 + j];
            }
        }
        bf2 w{__float2bfloat16(v0), __float2bfloat16(v1)};
        *(bf2*)(xt + ((size_t)chunk * NROW + bid) * 608 + r * 2) = w;
    }
}

// ---------------------------------------------------------------------------
// Conv (R13/R20 verbatim, verified ~107us). Grid 512 (2 blocks/CU).
// ---------------------------------------------------------------------------
__global__ __launch_bounds__(256, 2) void conv_mfma_kernel(
    const __hip_bfloat16* __restrict__ xt,
    const __hip_bfloat16* __restrict__ wl,
    __hip_bfloat16* __restrict__ y4b)
{
    __shared__ __align__(16) char lds[LDS_SZ];

    const int phys = blockIdx.x;
    const int bid  = (phys & 7) * (64 * KSN / 8) + (phys >> 3);

    const int low3 = bid & 7;
    const int rest = bid >> 3;
    const int ks   = rest % KSN;
    const int mb   = (rest / KSN) * 8 + low3;   // 0..63
    const int b    = mb >> 4;                   // 0..3
    const int oz   = mb & 15;                   // z-out 0..15

    const int tid  = threadIdx.x;
    const int w    = tid >> 6;
    const int lane = tid & 63;
    const int m    = lane & 31;
    const int h    = lane >> 5;

    int invAE[6]; int nAE = 0;
#pragma unroll
    for (int k = 0; k < 6; ++k) {
        const int i = w + 4 * k;
        if (i < 23) {
            const int o = i * 1024 + lane * 16;
            int r = o / AROW;
            int rem = o - r * AROW;
            if (r > AE_ROWS - 1) { r = AE_ROWS - 1; rem = 0; }
            if (rem >= 1216) rem = 0;
            const int s  = rem >> 5;
            const int cg = ((rem >> 4) & 1) ^ ((s >> 1) & 1);
            invAE[k] = (2 * r) * 608 + s * 16 + cg * 8;
            nAE = k + 1;
        }
    }
    int invAO[6]; int nAO = 0;
#pragma unroll
    for (int k = 0; k < 6; ++k) {
        const int i = w + 4 * k;
        if (i < 22) {
            const int o = i * 1024 + lane * 16;
            int r = o / AROW;
            int rem = o - r * AROW;
            if (r > AO_ROWS - 1) { r = AO_ROWS - 1; rem = 0; }
            if (rem >= 1216) rem = 0;
            const int s  = rem >> 5;
            const int cg = ((rem >> 4) & 1) ^ ((s >> 1) & 1);
            invAO[k] = (2 * r + 1) * 608 + s * 16 + cg * 8;
            nAO = k + 1;
        }
    }
    int invB[4]; int nB = 0;
#pragma unroll
    for (int k = 0; k < 4; ++k) {
        const int i = w + 4 * k;
        if (i < 14) {
            const int kx = i >> 1, nt = i & 1;
            invB[k] = kx * 1024 + (nt * 32 + m) * 16 + h * 8;
            nB = k + 1;
        }
    }

    f16v acc[2][2];
    for (int t = 0; t < 2; ++t)
        for (int n = 0; n < 2; ++n)
            for (int k = 0; k < 16; ++k) acc[t][n][k] = 0.f;

    const int rA0   = ((m >> 4) << 2) + ((m >> 2) & 3);
    const int sbase = (w << 3) + ((m & 3) << 1);

    auto stageAE = [&](int g) {
        const int chunk = g / 7, kz = g - chunk * 7;
        const size_t u = ((size_t)chunk * NROW
                        + (size_t)(b * PZ_ + 2 * oz + kz) * PZ_) * 608;
#pragma unroll
        for (int k = 0; k < 6; ++k)
            if (k < nAE) gl_lds16(xt + u + invAE[k], lds + (w + 4 * k) * 1024);
    };
    auto stageAO = [&](int g) {
        const int chunk = g / 7, kz = g - chunk * 7;
        const size_t u = ((size_t)chunk * NROW
                        + (size_t)(b * PZ_ + 2 * oz + kz) * PZ_) * 608;
#pragma unroll
        for (int k = 0; k < 6; ++k)
            if (k < nAO) gl_lds16(xt + u + invAO[k], lds + AO_OFF + (w + 4 * k) * 1024);
    };
    auto stageB = [&](int g, int kyv, int bsel) {
        const int chunk = g / 7, kz = g - chunk * 7;
        const size_t u = ((size_t)chunk * NTAP + (size_t)(kz * 7 + kyv) * 7) * 1024;
        char* dst = lds + B_OFF + bsel * BSZ;
#pragma unroll
        for (int k = 0; k < 4; ++k)
            if (k < nB) gl_lds16(wl + u + invB[k], dst + (w + 4 * k) * 1024);
    };

    auto compute = [&](int ky, int bsel) {
        const int abase = (ky & 1) ? AO_OFF : 0;
        const char* abp = lds + abase + (rA0 + (ky >> 1)) * AROW;
        const char* bbp = lds + B_OFF + bsel * BSZ;
#pragma unroll
        for (int kx = 0; kx < 7; ++kx) {
            const int s   = sbase + kx;
            const int cgp = h ^ ((s >> 1) & 1);
            const char* ap = abp + s * 32 + cgp * 16;
            const s8 a0 = *(const s8*)(ap);
            const s8 a1 = *(const s8*)(ap + 8 * AROW);
            const char* bp = bbp + kx * 2048 + h * 512 + m * 16;
            const s8 b0 = *(const s8*)(bp);
            const s8 b1 = *(const s8*)(bp + 1024);
            acc[0][0] = __builtin_amdgcn_mfma_f32_32x32x16_bf16(a0, b0, acc[0][0], 0, 0, 0);
            acc[0][1] = __builtin_amdgcn_mfma_f32_32x32x16_bf16(a0, b1, acc[0][1], 0, 0, 0);
            acc[1][0] = __builtin_amdgcn_mfma_f32_32x32x16_bf16(a1, b0, acc[1][0], 0, 0, 0);
            acc[1][1] = __builtin_amdgcn_mfma_f32_32x32x16_bf16(a1, b1, acc[1][1], 0, 0, 0);
        }
    };

    const int G = (70 - ks + KSN - 1) / KSN;
    const int T = G * 7;
    stageAO(ks);
    stageB(ks, 1, 0);
    __syncthreads();
    int bB = 0;
    for (int t = 0; t < T; ++t) {
        const int gi = t / 7, p = t - gi * 7;
        const int g  = ks + gi * KSN;
        const int ky = (p < 3) ? (2 * p + 1) : (2 * (p - 3));
        const int tn = t + 1;
        if (tn < T) {
            const int gin = tn / 7, pn = tn - gin * 7;
            const int kyn = (pn < 3) ? (2 * pn + 1) : (2 * (pn - 3));
            stageB(ks + gin * KSN, kyn, bB ^ 1);
        }
        if (p == 0) stageAE(g);
        else if (p == 3 && g + KSN < 70) stageAO(g + KSN);
        compute(ky, bB);
        __syncthreads();
        bB ^= 1;
    }

    // epilogue: two-pass LDS transpose, coalesced bf16 partial stores
    const int nl = lane & 31;
    f4* yb = (f4*)lds;
    __hip_bfloat16* dst0 = y4b + (size_t)ks * SLICE_E + (size_t)(b * 64) * 4096;
#pragma unroll
    for (int t = 0; t < 2; ++t) {
        __syncthreads();
#pragma unroll
        for (int nt = 0; nt < 2; ++nt) {
            const int n = nt * 32 + nl;
#pragma unroll
            for (int q = 0; q < 4; ++q) {
                const int rr = 2 * q + h;
                f4 v = { acc[t][nt][4*q], acc[t][nt][4*q+1],
                         acc[t][nt][4*q+2], acc[t][nt][4*q+3] };
                yb[n * 33 + rr * 4 + w] = v;
            }
        }
        __syncthreads();
        for (int j = tid; j < 2048; j += 256) {
            const int n  = j >> 5, sp = j & 31;
            f4 v = yb[n * 33 + sp];
            const int rr = sp >> 2, wq = sp & 3;
            const int yo = t * 8 + (rr >> 2) * 4 + (rr & 3);
            bh4 p{__float2bfloat16(v.x), __float2bfloat16(v.y),
                  __float2bfloat16(v.z), __float2bfloat16(v.w)};
            *(bh4*)(dst0 + (size_t)n * 4096 + oz * 256 + yo * 16 + wq * 4) = p;
        }
    }
}

// ---------------------------------------------------------------------------
// Fused combine+finalize. Grid 256 (all blocks resident -> spin-safe).
// Phase1: sum KSN slices into REGISTERS + block sum-of-squares -> sums2.
// Grid sync via device-scope counter. Phase2: normalize registers -> out.
// ---------------------------------------------------------------------------
__global__ void combine_finalize_kernel(const __hip_bfloat16* __restrict__ y4b,
                                        const float* __restrict__ g_s,
                                        const float* __restrict__ g_v,
                                        const float* __restrict__ bias_s,
                                        float* __restrict__ out,
                                        float* __restrict__ sums2,
                                        int* __restrict__ counter)
{
    const int tid = threadIdx.x;
    const int n = blockIdx.x & 63, q = blockIdx.x >> 6;
    const size_t base = ((size_t)q * 64 + n) * 4096;

    float s = 0.f;
    f4 v0, v1, v2, v3;
#define SUMSLICES(VV, IT) {                                                   \
        const size_t off = base + (size_t)(tid + (IT) * 256) * 4;             \
        f4 v = {0.f, 0.f, 0.f, 0.f};                                          \
        _Pragma("unroll")                                                     \
        for (int k = 0; k < KSN; ++k) {                                       \
            bh4 r = *(const bh4*)(y4b + off + (size_t)k * SLICE_E);           \
            v.x += (float)r.x; v.y += (float)r.y;                             \
            v.z += (float)r.z; v.w += (float)r.w;                             \
        }                                                                     \
        VV = v;                                                               \
        s += v.x*v.x + v.y*v.y + v.z*v.z + v.w*v.w;                           \
    }
    SUMSLICES(v0, 0) SUMSLICES(v1, 1) SUMSLICES(v2, 2) SUMSLICES(v3, 3)
#undef SUMSLICES

    __shared__ float red[256];
    red[tid] = s;
    __syncthreads();
    for (int st = 128; st > 0; st >>= 1) {
        if (tid < st) red[tid] += red[tid + st];
        __syncthreads();
    }
    if (tid == 0) {
        __hip_atomic_store(&sums2[n * 4 + q], red[0],
                           __ATOMIC_RELAXED, __HIP_MEMORY_SCOPE_AGENT);
        __threadfence();                     // release sums2 to device scope
        atomicAdd(counter, 1);               // device-scope by default
        while (__hip_atomic_load(counter, __ATOMIC_ACQUIRE,
                                 __HIP_MEMORY_SCOPE_AGENT) < 256) {}
    }
    __syncthreads();                         // all threads see counter==256

    float scale = 0.f, bias = 0.f;
    bool do_relu = false;
    if (n < 16) {
        float sum = 0.f;
#pragma unroll
        for (int k = 0; k < 4; ++k)
            sum += __hip_atomic_load(&sums2[n * 4 + k],
                                     __ATOMIC_RELAXED, __HIP_MEMORY_SCOPE_AGENT);
        const float var = sum * (1.0f / 16384.0f);
        scale = g_s[n] / sqrtf(var + 1e-5f);
        bias = bias_s[n];
        do_relu = true;
    } else {
        const int u = (n - 16) / 3;
        float sum = 0.f;
#pragma unroll
        for (int k = 0; k < 12; ++k)
            sum += __hip_atomic_load(&sums2[(16 + u * 3) * 4 + k],
                                     __ATOMIC_RELAXED, __HIP_MEMORY_SCOPE_AGENT);
        const float var = sum * (1.0f / 49152.0f);
        scale = g_v[u] / sqrtf(var + 1e-5f);
    }

#define WRITEOUT(VV, IT) {                                                    \
        const size_t off = base + (size_t)(tid + (IT) * 256) * 4;             \
        f4 o;                                                                 \
        o.x = VV.x * scale + bias; o.y = VV.y * scale + bias;                 \
        o.z = VV.z * scale + bias; o.w = VV.w * scale + bias;                 \
        if (do_relu) {                                                        \
            o.x = fmaxf(o.x, 0.f); o.y = fmaxf(o.y, 0.f);                     \
            o.z = fmaxf(o.z, 0.f); o.w = fmaxf(o.w, 0.f);                     \
        }                                                                     \
        *(f4*)(out + off) = o;                                                \
    }
    WRITEOUT(v0, 0) WRITEOUT(v1, 1) WRITEOUT(v2, 2) WRITEOUT(v3, 3)
#undef WRITEOUT
}

// ---------------------------------------------------------------------------
extern "C" void kernel_launch(void* const* d_in, const int* in_sizes, int n_in,
                              void* d_out, int out_size, void* d_ws, size_t ws_size,
                              hipStream_t stream)
{
    const float* sv    = (const float*)d_in[0];
    const float* b_ss  = (const float*)d_in[1];
    const float* w_ss  = (const float*)d_in[2];
    const float* b_sv  = (const float*)d_in[3];
    const float* w_sv  = (const float*)d_in[4];
    const float* b_st  = (const float*)d_in[5];
    const float* w_st  = (const float*)d_in[6];
    const float* b_vs  = (const float*)d_in[7];
    const float* w_vs  = (const float*)d_in[8];
    const float* b_vv  = (const float*)d_in[9];
    const float* w_vv  = (const float*)d_in[10];
    const float* b_vt  = (const float*)d_in[11];
    const float* w_vt  = (const float*)d_in[12];
    const float* bn_gs = (const float*)d_in[13];
    const float* bn_gv = (const float*)d_in[14];
    const float* bias_s= (const float*)d_in[15];
    float* out = (float*)d_out;

    char* ws = (char*)d_ws;
    constexpr size_t XT_BYTES = (size_t)10 * NROW * 1216;      // 66,588,160
    constexpr size_t WL_BYTES = (size_t)10 * NTAP * 2048;      //  7,024,640
    constexpr size_t Y4_BYTES = (size_t)KSN * SLICE_E * 2;     // 16,777,216
    constexpr size_t S2_BYTES = 256 * 4;                       //      1,024

    __hip_bfloat16* xt  = (__hip_bfloat16*)ws;
    __hip_bfloat16* wl  = (__hip_bfloat16*)(ws + XT_BYTES);
    __hip_bfloat16* y4b = (__hip_bfloat16*)(ws + XT_BYTES + WL_BYTES);
    float* sums2 = (float*)(ws + XT_BYTES + WL_BYTES + Y4_BYTES);
    int*   counter = (int*)(ws + XT_BYTES + WL_BYTES + Y4_BYTES + S2_BYTES);

    hipMemsetAsync(counter, 0, 4, stream);
    build_xt_kernel<<<5476, 256, 0, stream>>>(sv, xt);
    build_w_kernel<<<343, 192, 0, stream>>>(
        b_ss, w_ss, b_sv, w_sv, b_st, w_st, b_vs, w_vs, b_vv, w_vv,
        b_vt, w_vt, wl);
    conv_mfma_kernel<<<64 * KSN, 256, 0, stream>>>(xt, wl, y4b);
    combine_finalize_kernel<<<256, 256, 0, stream>>>(
        y4b, bn_gs, bn_gv, bias_s, out, sums2, counter);
}

// Round 14
// 247.027 us; speedup vs baseline: 1.0479x; 1.0453x over previous
//
#include <hip/hip_runtime.h>
#include <hip/hip_bf16.h>

// ---------------------------------------------------------------------------
// Equivariant conv block. MFMA 32x32x16 implicit GEMM.
// R22 post-mortem: fused combine+finalize REGRESSED +6us (spin+memset) ->
// reverted to R20's separate tail (252.2 verified). R23 lever: conv A-read
// bank conflicts (7.02M cyc = ~11.4us/CU of conv's 106). Derivation: LDS
// unit u16=2s+cgp, group=(5row+u16)%8; same-row lanes give {0,5,0,5} and
// row r aliases row r-1 -> 4-way on every ds_read_b128. Fix: both-sides
// involution (rule #21): pre-swizzle the GLOBAL source per 16B unit with
// pi = swap(b0<->b2, b1<->b3) within 16-unit blocks (identity on partial
// block >=64), same pi on the read address. Reader still fetches global
// unit 2s+h -> correctness is layout-only. Row-quads now hit 4 distinct
// groups (was 2); residual <=2-way.
// ---------------------------------------------------------------------------

using f4  = __attribute__((ext_vector_type(4)))  float;
using f16v= __attribute__((ext_vector_type(16))) float;
using s8  = __attribute__((ext_vector_type(8)))  short;  // 8 bf16

#define C_TOT 160
#define PZ_   37
#define NTAP  343
#define NROW  (4 * PZ_ * PZ_)   // 5476 (b,z,y) rows per chunk
#define KSN   8
#define SLICE_E 1048576         // bf16 elems per partial slice (4*64*4096)

#define AROW    1232
#define AE_ROWS 19
#define AO_ROWS 18
#define AO_OFF  23552
#define B_OFF   46080
#define BSZ     14336
#define LDS_SZ  (B_OFF + 2 * BSZ)   // 74752

__device__ __forceinline__ void gl_lds16(const void* g, void* l) {
    __builtin_amdgcn_global_load_lds(
        (const __attribute__((address_space(1))) unsigned int*)g,
        (__attribute__((address_space(3))) unsigned int*)l, 16, 0, 0);
}

__device__ __forceinline__ void pair_ij(int p, int& i, int& j) {
    if (p < 3)      { i = p; j = p; }
    else if (p == 3){ i = 0; j = 1; }
    else if (p == 4){ i = 0; j = 2; }
    else            { i = 1; j = 2; }
}

// Bank-spread involution on 16B-unit index within a 1216B row (76 units).
// Swap bit pairs (b0<->b2, b1<->b3) inside each aligned 16-unit block;
// identity on the partial block (units 64..75). Involution: pi(pi(x))=x.
__device__ __forceinline__ int swz_u16(int u) {
    if (u < 64) {
        const int t = u & 15;
        return (u & ~15) | ((t & 3) << 2) | (t >> 2);
    }
    return u;
}

struct bf2 { __hip_bfloat16 x, y; };
struct bh4 { __hip_bfloat16 x, y, z, w; };

// ---------------------------------------------------------------------------
// build_w (R20): grid 343 = 1 block/tap, 192 threads.
// ---------------------------------------------------------------------------
__global__ void build_w_kernel(
    const float* __restrict__ b_ss, const float* __restrict__ w_ss,
    const float* __restrict__ b_sv, const float* __restrict__ w_sv,
    const float* __restrict__ b_st, const float* __restrict__ w_st,
    const float* __restrict__ b_vs, const float* __restrict__ w_vs,
    const float* __restrict__ b_vv, const float* __restrict__ w_vv,
    const float* __restrict__ b_vt, const float* __restrict__ w_vt,
    __hip_bfloat16* __restrict__ wl)
{
    __shared__ float S[13056];
    const int tid = threadIdx.x;          // 0..191
    const int tap = blockIdx.x;           // 0..342
    float* L = S;                         // 750
    float* W = S + 768;                   // 12288
    for (int r = tid; r < 750; r += 192) {
        float v;
        if (r < 3)        v = b_ss[r * NTAP + tap];
        else if (r < 12)  v = b_sv[(r - 3) * NTAP + tap];
        else if (r < 93)  v = b_st[(r - 12) * NTAP + tap];
        else if (r < 102) v = b_vs[(r - 93) * NTAP + tap];
        else if (r < 183) v = b_vv[(r - 102) * NTAP + tap];
        else              v = b_vt[(r - 183) * NTAP + tap];
        L[r] = v;
    }
    for (int r = tid; r < 12288; r += 192) {
        float v;
        if (r < 768)       v = w_ss[r];
        else if (r < 1536) v = w_sv[r - 768];
        else if (r < 3840) v = w_st[r - 1536];
        else if (r < 4608) v = w_vs[r - 3840];
        else if (r < 6912) v = w_vv[r - 4608];
        else               v = w_vt[r - 6912];
        W[r] = v;
    }
    __syncthreads();

    if (tid < 160) {
        const int c = tid;
        const int chunk = c >> 4, cw = c & 15;
        __hip_bfloat16* dst = wl + ((size_t)chunk * NTAP + tap) * 1024 + cw;

        if (c < 16) {
            const float l0 = L[0], l1 = L[1], l2 = L[2];
#pragma unroll
            for (int n = 0; n < 16; ++n) {
                const float* wr = &W[(n * 16 + c) * 3];
                dst[n * 16] = __float2bfloat16(wr[0]*l0 + wr[1]*l1 + wr[2]*l2);
            }
            float bv[3][3];
#pragma unroll
            for (int dn = 0; dn < 3; ++dn)
#pragma unroll
                for (int t = 0; t < 3; ++t) bv[dn][t] = L[93 + t*3 + dn];
#pragma unroll
            for (int u = 0; u < 16; ++u) {
                const float* wr = &W[3840 + (u * 16 + c) * 3];
                const float w0 = wr[0], w1 = wr[1], w2 = wr[2];
#pragma unroll
                for (int dn = 0; dn < 3; ++dn)
                    dst[(16 + u*3 + dn) * 16] = __float2bfloat16(
                        w0*bv[dn][0] + w1*bv[dn][1] + w2*bv[dn][2]);
            }
        } else if (c < 64) {
            const int mm = (c - 16) / 3, di = (c - 16) % 3;
            float bs0[3];
#pragma unroll
            for (int t = 0; t < 3; ++t) bs0[t] = L[3 + t*3 + di];
#pragma unroll
            for (int n = 0; n < 16; ++n) {
                const float* wr = &W[768 + (n * 16 + mm) * 3];
                dst[n * 16] = __float2bfloat16(
                    wr[0]*bs0[0] + wr[1]*bs0[1] + wr[2]*bs0[2]);
            }
            float bv[3][9];
#pragma unroll
            for (int dn = 0; dn < 3; ++dn)
#pragma unroll
                for (int t = 0; t < 9; ++t)
                    bv[dn][t] = L[102 + (t*3 + dn)*3 + di];
#pragma unroll
            for (int u = 0; u < 16; ++u) {
                const float* wr = &W[4608 + (u * 16 + mm) * 9];
                float a0 = 0.f, a1 = 0.f, a2 = 0.f;
#pragma unroll
                for (int t = 0; t < 9; ++t) {
                    const float wv = wr[t];
                    a0 += wv * bv[0][t]; a1 += wv * bv[1][t]; a2 += wv * bv[2][t];
                }
                dst[(16 + u*3 + 0) * 16] = __float2bfloat16(a0);
                dst[(16 + u*3 + 1) * 16] = __float2bfloat16(a1);
                dst[(16 + u*3 + 2) * 16] = __float2bfloat16(a2);
            }
        } else {
            const int q = c - 64, mm = q / 6, p = q % 6;
            int i, jj; pair_ij(p, i, jj);
            const int d1 = i*3 + jj, d2 = jj*3 + i;
            const bool dbl = (i != jj);
            float bs0[9];
#pragma unroll
            for (int t = 0; t < 9; ++t) {
                float b = L[12 + t*9 + d1];
                if (dbl) b += L[12 + t*9 + d2];
                bs0[t] = b;
            }
#pragma unroll
            for (int n = 0; n < 16; ++n) {
                const float* wr = &W[1536 + (n * 16 + mm) * 9];
                float acc = 0.f;
#pragma unroll
                for (int t = 0; t < 9; ++t) acc += wr[t] * bs0[t];
                dst[n * 16] = __float2bfloat16(acc);
            }
            float bv0[21], bv1[21], bv2[21];
#pragma unroll
            for (int t = 0; t < 21; ++t) {
                float x0 = L[183 + (t*3 + 0)*9 + d1];
                float x1 = L[183 + (t*3 + 1)*9 + d1];
                float x2 = L[183 + (t*3 + 2)*9 + d1];
                if (dbl) {
                    x0 += L[183 + (t*3 + 0)*9 + d2];
                    x1 += L[183 + (t*3 + 1)*9 + d2];
                    x2 += L[183 + (t*3 + 2)*9 + d2];
                }
                bv0[t] = x0; bv1[t] = x1; bv2[t] = x2;
            }
#pragma unroll
            for (int u = 0; u < 16; ++u) {
                const float* wr = &W[6912 + (u * 16 + mm) * 21];
                float a0 = 0.f, a1 = 0.f, a2 = 0.f;
#pragma unroll
                for (int t = 0; t < 21; ++t) {
                    const float wv = wr[t];
                    a0 += wv * bv0[t]; a1 += wv * bv1[t]; a2 += wv * bv2[t];
                }
                dst[(16 + u*3 + 0) * 16] = __float2bfloat16(a0);
                dst[(16 + u*3 + 1) * 16] = __float2bfloat16(a1);
                dst[(16 + u*3 + 2) * 16] = __float2bfloat16(a2);
            }
        }
    }
}

// ---------------------------------------------------------------------------
// build_xt: bid = (b*37 + z)*37 + y. xt[chunk][brow][s][16ch].
// ---------------------------------------------------------------------------
__global__ void build_xt_kernel(
    const float* __restrict__ sv, __hip_bfloat16* __restrict__ xt)
{
    __shared__ float row[2112];                  // 32*66
    const int tid = threadIdx.x;
    const int bid = blockIdx.x;                  // (b*37 + z)*37 + y
    const int y = bid % 37, z = (bid / 37) % 37, b = bid / 1369;
    const bool interior = (z >= 3 && z < 35 && y >= 3 && y < 35);
    if (interior) {
        const float* src = sv + (size_t)b * 2097152 + (z-3) * 1024 + (y-3) * 32;
        for (int f = tid; f < 2048; f += 256) {
            int ch = f >> 5, x = f & 31;
            row[x * 66 + ch] = src[(size_t)ch * 32768 + x];
        }
    }
    __syncthreads();
    for (int e2 = tid; e2 < 3040; e2 += 256) {
        const int chunk = e2 / 304;              // 0..9
        const int r     = e2 - chunk * 304;      // 0..303
        const int s     = r >> 3;                // 0..37
        const int cw    = (r & 7) * 2;
        const int c     = chunk * 16 + cw;
        float v0 = 0.f, v1 = 0.f;
        if (interior && s >= 3 && s < 35) {
            const int x = s - 3;
            if (c < 64) {
                v0 = row[x * 66 + c];
                v1 = row[x * 66 + c + 1];
            } else {
                int q = c - 64, u = q / 6, p = q % 6, i, j;
                pair_ij(p, i, j);
                v0 = row[x * 66 + 16 + u * 3 + i] * row[x * 66 + 16 + u * 3 + j];
                pair_ij(p + 1, i, j);
                v1 = row[x * 66 + 16 + u * 3 + i] * row[x * 66 + 16 + u * 3 + j];
            }
        }
        bf2 w{__float2bfloat16(v0), __float2bfloat16(v1)};
        *(bf2*)(xt + ((size_t)chunk * NROW + bid) * 608 + r * 2) = w;
    }
}

// ---------------------------------------------------------------------------
// Conv. Grid 512 (2 blocks/CU). R23: bank-conflict swizzle on A path.
// LDS 16B-unit u holds global unit pi(u); reader computes pi(2s+h).
// ---------------------------------------------------------------------------
__global__ __launch_bounds__(256, 2) void conv_mfma_kernel(
    const __hip_bfloat16* __restrict__ xt,
    const __hip_bfloat16* __restrict__ wl,
    __hip_bfloat16* __restrict__ y4b)
{
    __shared__ __align__(16) char lds[LDS_SZ];

    const int phys = blockIdx.x;
    const int bid  = (phys & 7) * (64 * KSN / 8) + (phys >> 3);

    const int low3 = bid & 7;
    const int rest = bid >> 3;
    const int ks   = rest % KSN;
    const int mb   = (rest / KSN) * 8 + low3;   // 0..63
    const int b    = mb >> 4;                   // 0..3
    const int oz   = mb & 15;                   // z-out 0..15

    const int tid  = threadIdx.x;
    const int w    = tid >> 6;
    const int lane = tid & 63;
    const int m    = lane & 31;
    const int h    = lane >> 5;

    // ---- A staging source offsets: LDS unit u holds global unit pi(u) ----
    int invAE[6]; int nAE = 0;
#pragma unroll
    for (int k = 0; k < 6; ++k) {
        const int i = w + 4 * k;
        if (i < 23) {
            const int o = i * 1024 + lane * 16;
            int r = o / AROW;
            int rem = o - r * AROW;
            if (r > AE_ROWS - 1) { r = AE_ROWS - 1; rem = 0; }
            if (rem >= 1216) rem = 0;
            const int gu = swz_u16(rem >> 4);
            invAE[k] = (2 * r) * 608 + gu * 8;
            nAE = k + 1;
        }
    }
    int invAO[6]; int nAO = 0;
#pragma unroll
    for (int k = 0; k < 6; ++k) {
        const int i = w + 4 * k;
        if (i < 22) {
            const int o = i * 1024 + lane * 16;
            int r = o / AROW;
            int rem = o - r * AROW;
            if (r > AO_ROWS - 1) { r = AO_ROWS - 1; rem = 0; }
            if (rem >= 1216) rem = 0;
            const int gu = swz_u16(rem >> 4);
            invAO[k] = (2 * r + 1) * 608 + gu * 8;
            nAO = k + 1;
        }
    }
    int invB[4]; int nB = 0;
#pragma unroll
    for (int k = 0; k < 4; ++k) {
        const int i = w + 4 * k;
        if (i < 14) {
            const int kx = i >> 1, nt = i & 1;
            invB[k] = kx * 1024 + (nt * 32 + m) * 16 + h * 8;
            nB = k + 1;
        }
    }

    f16v acc[2][2];
    for (int t = 0; t < 2; ++t)
        for (int n = 0; n < 2; ++n)
            for (int k = 0; k < 16; ++k) acc[t][n][k] = 0.f;

    const int rA0   = ((m >> 4) << 2) + ((m >> 2) & 3);
    const int sbase = (w << 3) + ((m & 3) << 1);

    // ---- A-read byte offsets within row (swizzled), per kx ----
    int luB[7];
#pragma unroll
    for (int kx = 0; kx < 7; ++kx) {
        const int g = 2 * (sbase + kx) + h;     // global 16B unit 0..75
        luB[kx] = swz_u16(g) * 16;
    }

    auto stageAE = [&](int g) {
        const int chunk = g / 7, kz = g - chunk * 7;
        const size_t u = ((size_t)chunk * NROW
                        + (size_t)(b * PZ_ + 2 * oz + kz) * PZ_) * 608;
#pragma unroll
        for (int k = 0; k < 6; ++k)
            if (k < nAE) gl_lds16(xt + u + invAE[k], lds + (w + 4 * k) * 1024);
    };
    auto stageAO = [&](int g) {
        const int chunk = g / 7, kz = g - chunk * 7;
        const size_t u = ((size_t)chunk * NROW
                        + (size_t)(b * PZ_ + 2 * oz + kz) * PZ_) * 608;
#pragma unroll
        for (int k = 0; k < 6; ++k)
            if (k < nAO) gl_lds16(xt + u + invAO[k], lds + AO_OFF + (w + 4 * k) * 1024);
    };
    auto stageB = [&](int g, int kyv, int bsel) {
        const int chunk = g / 7, kz = g - chunk * 7;
        const size_t u = ((size_t)chunk * NTAP + (size_t)(kz * 7 + kyv) * 7) * 1024;
        char* dst = lds + B_OFF + bsel * BSZ;
#pragma unroll
        for (int k = 0; k < 4; ++k)
            if (k < nB) gl_lds16(wl + u + invB[k], dst + (w + 4 * k) * 1024);
    };

    auto compute = [&](int ky, int bsel) {
        const int abase = (ky & 1) ? AO_OFF : 0;
        const char* abp = lds + abase + (rA0 + (ky >> 1)) * AROW;
        const char* bbp = lds + B_OFF + bsel * BSZ;
#pragma unroll
        for (int kx = 0; kx < 7; ++kx) {
            const char* ap = abp + luB[kx];
            const s8 a0 = *(const s8*)(ap);
            const s8 a1 = *(const s8*)(ap + 8 * AROW);
            const char* bp = bbp + kx * 2048 + h * 512 + m * 16;
            const s8 b0 = *(const s8*)(bp);
            const s8 b1 = *(const s8*)(bp + 1024);
            acc[0][0] = __builtin_amdgcn_mfma_f32_32x32x16_bf16(a0, b0, acc[0][0], 0, 0, 0);
            acc[0][1] = __builtin_amdgcn_mfma_f32_32x32x16_bf16(a0, b1, acc[0][1], 0, 0, 0);
            acc[1][0] = __builtin_amdgcn_mfma_f32_32x32x16_bf16(a1, b0, acc[1][0], 0, 0, 0);
            acc[1][1] = __builtin_amdgcn_mfma_f32_32x32x16_bf16(a1, b1, acc[1][1], 0, 0, 0);
        }
    };

    const int G = (70 - ks + KSN - 1) / KSN;
    const int T = G * 7;
    stageAO(ks);
    stageB(ks, 1, 0);
    __syncthreads();
    int bB = 0;
    for (int t = 0; t < T; ++t) {
        const int gi = t / 7, p = t - gi * 7;
        const int g  = ks + gi * KSN;
        const int ky = (p < 3) ? (2 * p + 1) : (2 * (p - 3));
        const int tn = t + 1;
        if (tn < T) {
            const int gin = tn / 7, pn = tn - gin * 7;
            const int kyn = (pn < 3) ? (2 * pn + 1) : (2 * (pn - 3));
            stageB(ks + gin * KSN, kyn, bB ^ 1);
        }
        if (p == 0) stageAE(g);
        else if (p == 3 && g + KSN < 70) stageAO(g + KSN);
        compute(ky, bB);
        __syncthreads();
        bB ^= 1;
    }

    // epilogue: two-pass LDS transpose, coalesced bf16 partial stores
    const int nl = lane & 31;
    f4* yb = (f4*)lds;
    __hip_bfloat16* dst0 = y4b + (size_t)ks * SLICE_E + (size_t)(b * 64) * 4096;
#pragma unroll
    for (int t = 0; t < 2; ++t) {
        __syncthreads();
#pragma unroll
        for (int nt = 0; nt < 2; ++nt) {
            const int n = nt * 32 + nl;
#pragma unroll
            for (int q = 0; q < 4; ++q) {
                const int rr = 2 * q + h;
                f4 v = { acc[t][nt][4*q], acc[t][nt][4*q+1],
                         acc[t][nt][4*q+2], acc[t][nt][4*q+3] };
                yb[n * 33 + rr * 4 + w] = v;
            }
        }
        __syncthreads();
        for (int j = tid; j < 2048; j += 256) {
            const int n  = j >> 5, sp = j & 31;
            f4 v = yb[n * 33 + sp];
            const int rr = sp >> 2, wq = sp & 3;
            const int yo = t * 8 + (rr >> 2) * 4 + (rr & 3);
            bh4 p{__float2bfloat16(v.x), __float2bfloat16(v.y),
                  __float2bfloat16(v.z), __float2bfloat16(v.w)};
            *(bh4*)(dst0 + (size_t)n * 4096 + oz * 256 + yo * 16 + wq * 4) = p;
        }
    }
}

// ---------------------------------------------------------------------------
// Combine KSN bf16 partials -> f32 yc + per-(n,b) sum of squares. 256 blocks.
// ---------------------------------------------------------------------------
__global__ void combine_reduce_kernel(const __hip_bfloat16* __restrict__ y4b,
                                      float* __restrict__ yc,
                                      float* __restrict__ sums2)
{
    const int n = blockIdx.x & 63, q = blockIdx.x >> 6;
    const size_t base = ((size_t)q * 64 + n) * 4096;
    float s = 0.f;
    for (int i = threadIdx.x; i < 1024; i += 256) {
        const size_t off = base + (size_t)i * 4;
        f4 v = {0.f, 0.f, 0.f, 0.f};
#pragma unroll
        for (int k = 0; k < KSN; ++k) {
            bh4 r = *(const bh4*)(y4b + off + (size_t)k * SLICE_E);
            v.x += (float)r.x; v.y += (float)r.y;
            v.z += (float)r.z; v.w += (float)r.w;
        }
        *(f4*)(yc + off) = v;
        s += v.x * v.x + v.y * v.y + v.z * v.z + v.w * v.w;
    }
    __shared__ float red[256];
    red[threadIdx.x] = s;
    __syncthreads();
    for (int st = 128; st > 0; st >>= 1) {
        if (threadIdx.x < st) red[threadIdx.x] += red[threadIdx.x + st];
        __syncthreads();
    }
    if (threadIdx.x == 0) sums2[n * 4 + q] = red[0];
}

// ---------------------------------------------------------------------------
__global__ void finalize_kernel(const float* __restrict__ yc,
                                const float* __restrict__ sums2,
                                const float* __restrict__ g_s,
                                const float* __restrict__ g_v,
                                const float* __restrict__ bias_s,
                                float* __restrict__ out)
{
    const int idx = blockIdx.x * 256 + threadIdx.x;   // exact grid, 1M
    const int n = (idx >> 12) & 63;
    float v = yc[idx];
    if (n < 16) {
        float sum = sums2[n*4] + sums2[n*4+1] + sums2[n*4+2] + sums2[n*4+3];
        float var = sum * (1.0f / 16384.0f);
        float sc  = g_s[n] / sqrtf(var + 1e-5f);
        v = fmaxf(v * sc + bias_s[n], 0.f);
    } else {
        int u = (n - 16) / 3;
        float sum = 0.f;
        for (int k = 0; k < 12; ++k) sum += sums2[(16 + u * 3) * 4 + k];
        float var = sum * (1.0f / 49152.0f);
        v = v * (g_v[u] / sqrtf(var + 1e-5f));
    }
    out[idx] = v;
}

// ---------------------------------------------------------------------------
extern "C" void kernel_launch(void* const* d_in, const int* in_sizes, int n_in,
                              void* d_out, int out_size, void* d_ws, size_t ws_size,
                              hipStream_t stream)
{
    const float* sv    = (const float*)d_in[0];
    const float* b_ss  = (const float*)d_in[1];
    const float* w_ss  = (const float*)d_in[2];
    const float* b_sv  = (const float*)d_in[3];
    const float* w_sv  = (const float*)d_in[4];
    const float* b_st  = (const float*)d_in[5];
    const float* w_st  = (const float*)d_in[6];
    const float* b_vs  = (const float*)d_in[7];
    const float* w_vs  = (const float*)d_in[8];
    const float* b_vv  = (const float*)d_in[9];
    const float* w_vv  = (const float*)d_in[10];
    const float* b_vt  = (const float*)d_in[11];
    const float* w_vt  = (const float*)d_in[12];
    const float* bn_gs = (const float*)d_in[13];
    const float* bn_gv = (const float*)d_in[14];
    const float* bias_s= (const float*)d_in[15];
    float* out = (float*)d_out;

    char* ws = (char*)d_ws;
    constexpr size_t XT_BYTES = (size_t)10 * NROW * 1216;      // 66,588,160
    constexpr size_t WL_BYTES = (size_t)10 * NTAP * 2048;      //  7,024,640
    constexpr size_t Y4_BYTES = (size_t)KSN * SLICE_E * 2;     // 16,777,216
    constexpr size_t YC_BYTES = (size_t)4 * 64 * 4096 * 4;     //  4,194,304

    __hip_bfloat16* xt  = (__hip_bfloat16*)ws;
    __hip_bfloat16* wl  = (__hip_bfloat16*)(ws + XT_BYTES);
    __hip_bfloat16* y4b = (__hip_bfloat16*)(ws + XT_BYTES + WL_BYTES);
    float* yc    = (float*)(ws + XT_BYTES + WL_BYTES + Y4_BYTES);
    float* sums2 = (float*)(ws + XT_BYTES + WL_BYTES + Y4_BYTES + YC_BYTES);

    build_xt_kernel<<<5476, 256, 0, stream>>>(sv, xt);
    build_w_kernel<<<343, 192, 0, stream>>>(
        b_ss, w_ss, b_sv, w_sv, b_st, w_st, b_vs, w_vs, b_vv, w_vv,
        b_vt, w_vt, wl);
    conv_mfma_kernel<<<64 * KSN, 256, 0, stream>>>(xt, wl, y4b);
    combine_reduce_kernel<<<256, 256, 0, stream>>>(y4b, yc, sums2);
    finalize_kernel<<<4096, 256, 0, stream>>>(yc, sums2, bn_gs, bn_gv, bias_s, out);
}